// Round 11
// baseline (2504.101 us; speedup 1.0000x reference)
//
#include <hip/hip_runtime.h>
#include <math.h>

// GCN generator: B=8, N=F=128. Round 11: TWO batches per block (4 blocks x
// 1024 threads) so independent work fills barrier/dependency stalls; G
// ping-pong buffers live in GLOBAL ws (L2-resident, 32KB each) freeing LDS
// for the 2nd batch's X/U and moving G reads off the saturated DS pipe.
// Same-CU global store->load coherence via write-through L1 + barrier
// vmcnt drain. Structure per step (both batches in each phase):
//   P2(a,b): z=(D M D)u + d^2 u fused + relu + ssq + z->X | B
//   P4(a,b): mm_a u=(dv.z).W -> U (all waves); probs by t<128 (a) and
//            t in [512,640) (b) - parallel serial-tails | B
//   P4c(a,b): degrees/diag, same thread split | B
// No persistent regs beyond W (32 VGPR) - rounds 3/10 spill lesson.

#define NN 128
#define SP 136
#define GS 128

typedef _Float16 f16;
typedef _Float16 f16x8 __attribute__((ext_vector_type(8)));
typedef _Float16 f16x4 __attribute__((ext_vector_type(4)));
typedef _Float16 f16x2 __attribute__((ext_vector_type(2)));
typedef float f32x4 __attribute__((ext_vector_type(4)));

__device__ __forceinline__ f32x4 mm(f16x8 a, f16x8 b, f32x4 c) {
    return __builtin_amdgcn_mfma_f32_16x16x32_f16(a, b, c, 0, 0, 0);
}

__device__ __forceinline__ float rowdot8(f16x8 g, float acc) {
#if __has_builtin(__builtin_amdgcn_fdot2)
    const f16x2 one2 = {(f16)1.0f, (f16)1.0f};
    #pragma unroll
    for (int p = 0; p < 4; ++p) {
        f16x2 pr = {g[2*p], g[2*p+1]};
        acc = __builtin_amdgcn_fdot2(pr, one2, acc, false);
    }
#else
    #pragma unroll
    for (int e = 0; e < 8; ++e) acc += (float)g[e];
#endif
    return acc;
}

__device__ __forceinline__ float dot8(f16x8 a, f16x8 b, float acc) {
#if __has_builtin(__builtin_amdgcn_fdot2)
    #pragma unroll
    for (int p = 0; p < 4; ++p) {
        f16x2 pa = {a[2*p], a[2*p+1]};
        f16x2 pb = {b[2*p], b[2*p+1]};
        acc = __builtin_amdgcn_fdot2(pa, pb, acc, false);
    }
#else
    #pragma unroll
    for (int e = 0; e < 8; ++e) acc += (float)a[e]*(float)b[e];
#endif
    return acc;
}

__global__ __launch_bounds__(1024)
void gcn_gen_kernel(const float* __restrict__ gx,
                    const float* __restrict__ gW,
                    const float* __restrict__ gb,
                    float* __restrict__ gout,
                    f16* __restrict__ gws)
{
    extern __shared__ char lds_raw[];
    const int PB = NN*SP;
    f16* p = (f16*)lds_raw;
    f16* Xs[2];  f16* Us[2];  f16* dfs[2];
    Xs[0] = p;            Us[0] = p + PB;
    Xs[1] = p + 2*PB;     Us[1] = p + 3*PB;
    dfs[0] = p + 4*PB;    dfs[1] = dfs[0] + NN;
    float* fp = (float*)(dfs[1] + NN);
    float* sd[2]; float* sdiag[2]; float* sprob[2]; float* srows[2]; float* sssq[2];
    sd[0]=fp;            sdiag[0]=sd[0]+NN;  sprob[0]=sdiag[0]+NN;
    srows[0]=sprob[0]+NN; sssq[0]=srows[0]+4*NN;
    sd[1]=sssq[0]+4*NN;  sdiag[1]=sd[1]+NN;  sprob[1]=sdiag[1]+NN;
    srows[1]=sprob[1]+NN; sssq[1]=srows[1]+4*NN;

    const int bid = blockIdx.x;
    const int t = threadIdx.x;
    const int lane = t & 63;
    const int w = t >> 6;
    const int wr = w >> 2, wc = w & 3;
    const int lrow = lane & 15;
    const int lgrp = lane >> 4;
    const int r0 = wr*32 + lrow;
    const int r1 = r0 + 16;

    const float* xbs[2]; float* outbs[2]; f16* Gb[2][2];
    #pragma unroll
    for (int bb = 0; bb < 2; ++bb) {
        const int g = bid*2 + bb;
        xbs[bb]   = gx   + (size_t)g*NN*NN;
        outbs[bb] = gout + (size_t)g*NN*NN;
        Gb[bb][0] = gws + (size_t)g*2*NN*GS;
        Gb[bb][1] = Gb[bb][0] + NN*GS;
    }

    const float bias0 = gb[wc*32 + lrow];
    const float bias1 = gb[wc*32 + 16 + lrow];

    // ---- W -> registers as B-fragments for mm_a (shared by both batches) ----
    f16x8 Wh[4][2];
    #pragma unroll
    for (int ks = 0; ks < 4; ++ks)
    #pragma unroll
    for (int ct = 0; ct < 2; ++ct) {
        const int col = wc*32 + ct*16 + lrow;
        #pragma unroll
        for (int r = 0; r < 8; ++r)
            Wh[ks][ct][r] = (f16)gW[(ks*32 + lgrp*8 + r)*NN + col];
    }

    // ---- init: X = f16(x), out = eye, G0 = I (global), vectors ----
    #pragma unroll
    for (int q = 0; q < 16; ++q) {
        int idx = q*1024 + t;
        int r = idx >> 7, c = idx & 127;
        float e = (r == c) ? 1.f : 0.f;
        #pragma unroll
        for (int bb = 0; bb < 2; ++bb) {
            Xs[bb][r*SP + c] = (f16)xbs[bb][idx];
            outbs[bb][idx] = e;
        }
    }
    {
        const int row = t >> 3, cb = (t & 7)*16;
        f16x8 e0, e1;
        #pragma unroll
        for (int e = 0; e < 8; ++e) {
            e0[e] = (f16)((cb + e     == row) ? 1.f : 0.f);
            e1[e] = (f16)((cb + 8 + e == row) ? 1.f : 0.f);
        }
        #pragma unroll
        for (int bb = 0; bb < 2; ++bb) {
            *(f16x8*)(Gb[bb][0] + row*GS + cb)     = e0;
            *(f16x8*)(Gb[bb][0] + row*GS + cb + 8) = e1;
        }
    }
    if (t < NN) {
        #pragma unroll
        for (int bb = 0; bb < 2; ++bb) {
            sd[bb][t] = 0.70710678f;
            dfs[bb][t] = (f16)0.70710678f;
            sdiag[bb][t] = 1.f;
        }
    }
    __syncthreads();

    // mm_a: u = (sv . X) . W -> U[fo][m]
    auto run_mma = [&](int bb, f16 sv0, f16 sv1) {
        f16* Xb = Xs[bb]; f16* Ub = Us[bb];
        f32x4 a2[2][2];
        #pragma unroll
        for (int rt = 0; rt < 2; ++rt)
        #pragma unroll
        for (int ct = 0; ct < 2; ++ct)
            a2[rt][ct] = (f32x4){0.f,0.f,0.f,0.f};
        #pragma unroll
        for (int ks = 0; ks < 4; ++ks) {
            const int ko = ks*32 + lgrp*8;
            f16x8 A0 = *(const f16x8*)(Xb + r0*SP + ko) * sv0;
            f16x8 A1 = *(const f16x8*)(Xb + r1*SP + ko) * sv1;
            a2[0][0] = mm(A0, Wh[ks][0], a2[0][0]);
            a2[0][1] = mm(A0, Wh[ks][1], a2[0][1]);
            a2[1][0] = mm(A1, Wh[ks][0], a2[1][0]);
            a2[1][1] = mm(A1, Wh[ks][1], a2[1][1]);
        }
        #pragma unroll
        for (int rt = 0; rt < 2; ++rt)
        #pragma unroll
        for (int ct = 0; ct < 2; ++ct) {
            f16x4 uv;
            #pragma unroll
            for (int q = 0; q < 4; ++q) uv[q] = (f16)a2[rt][ct][q];
            *(f16x4*)(Ub + (wc*32 + ct*16 + lrow)*SP + wr*32 + rt*16 + lgrp*4) = uv;
        }
    };

    auto P2 = [&](int bb, int i) {
        f16* Xb = Xs[bb]; f16* Ub = Us[bb]; f16* dfb = dfs[bb];
        const f16* Gc = Gb[bb][i & 1];
        f16* Gn = Gb[bb][(i & 1) ^ 1];
        f16x8 dcv[4];
        #pragma unroll
        for (int ks = 0; ks < 4; ++ks)
            dcv[ks] = *(const f16x8*)(dfb + ks*32 + lgrp*8);
        const f16 drh0 = dfb[r0];
        const f16 drh1 = dfb[r1];

        f32x4 acc[2][2];
        #pragma unroll
        for (int rt = 0; rt < 2; ++rt)
        #pragma unroll
        for (int ct = 0; ct < 2; ++ct)
            acc[rt][ct] = (f32x4){0.f,0.f,0.f,0.f};
        float rs0 = 0.f, rs1 = 0.f;
        #pragma unroll
        for (int ks = 0; ks < 4; ++ks) {
            const int ko = ks*32 + lgrp*8;
            f16x8 B0 = *(const f16x8*)(Ub + (wc*32 + lrow)*SP + ko) * dcv[ks];
            f16x8 B1 = *(const f16x8*)(Ub + (wc*32 + 16 + lrow)*SP + ko) * dcv[ks];
            f16x8 A0 = *(const f16x8*)(Gc + r0*GS + ko);
            f16x8 A1 = *(const f16x8*)(Gc + r1*GS + ko);
            acc[0][0] = mm(A0, B0, acc[0][0]);
            acc[0][1] = mm(A0, B1, acc[0][1]);
            acc[1][0] = mm(A1, B0, acc[1][0]);
            acc[1][1] = mm(A1, B1, acc[1][1]);
            if (ks == wc) {
                f16x8 G0s = A0 * dcv[ks] * drh0;
                f16x8 G1s = A1 * dcv[ks] * drh1;
                *(f16x8*)(Gn + r0*GS + ko) = G0s;
                *(f16x8*)(Gn + r1*GS + ko) = G1s;
                rs0 = rowdot8(G0s, rs0);
                rs1 = rowdot8(G1s, rs1);
            }
        }
        rs0 += __shfl_xor(rs0, 16); rs0 += __shfl_xor(rs0, 32);
        rs1 += __shfl_xor(rs1, 16); rs1 += __shfl_xor(rs1, 32);
        if (lgrp == 0) {
            srows[bb][wc*NN + r0] = rs0;
            srows[bb][wc*NN + r1] = rs1;
        }

        const float4 dr4a = *(const float4*)(sd[bb] + wr*32 + lgrp*4);
        const float4 dr4b = *(const float4*)(sd[bb] + wr*32 + 16 + lgrp*4);
        float z[2][2][4];
        #pragma unroll
        for (int rt = 0; rt < 2; ++rt)
        #pragma unroll
        for (int ct = 0; ct < 2; ++ct) {
            f16x4 u4 = *(const f16x4*)(Ub + (wc*32 + ct*16 + lrow)*SP
                                          + wr*32 + rt*16 + lgrp*4);
            const int col = wc*32 + ct*16 + lrow;
            #pragma unroll
            for (int q = 0; q < 4; ++q) {
                float dq = rt ? ((const float*)&dr4b)[q] : ((const float*)&dr4a)[q];
                float inner = fmaf(dq, (float)u4[q], acc[rt][ct][q]);
                float zv = fmaxf(fmaf(dq, inner, (ct ? bias1 : bias0)), 0.f);
                z[rt][ct][q] = zv;
                Xb[(wr*32 + rt*16 + lgrp*4 + q)*SP + col] = (f16)zv;
            }
        }
        {
            float ss[8];
            #pragma unroll
            for (int k = 0; k < 8; ++k) {
                float a = z[k>>2][0][k&3], c2 = z[k>>2][1][k&3];
                ss[k] = a*a + c2*c2;
            }
            #pragma unroll
            for (int k = 0; k < 8; ++k) {
                ss[k] += __shfl_xor(ss[k], 1);
                ss[k] += __shfl_xor(ss[k], 2);
                ss[k] += __shfl_xor(ss[k], 4);
                ss[k] += __shfl_xor(ss[k], 8);
            }
            if (lrow == 0) {
                #pragma unroll
                for (int k = 0; k < 8; ++k) {
                    int row = wr*32 + (k>>2)*16 + lgrp*4 + (k&3);
                    sssq[bb][wc*NN + row] = ss[k];
                }
            }
        }
    };

    auto P4 = [&](int bb, int i, int pn, float& p_keep) {
        float* ssq = sssq[bb];
        f16 dvh[2];
        #pragma unroll
        for (int rt = 0; rt < 2; ++rt) {
            const int row = wr*32 + rt*16 + lrow;
            float sq = ssq[row] + ssq[NN+row] + ssq[2*NN+row] + ssq[3*NN+row];
            float dv = (i == 0) ? 1.f : 1.f/(sqrtf(sq) + 1e-8f);
            dvh[rt] = (f16)fminf(dv, 60000.f);
        }
        run_mma(bb, dvh[0], dvh[1]);

        const int tloc = t - bb*512;
        if ((unsigned)tloc < NN) {
            const int tt = tloc;
            f16* Xb = Xs[bb];
            f16* Gn = Gb[bb][(i & 1) ^ 1];
            float sqp = ssq[pn] + ssq[NN+pn] + ssq[2*NN+pn] + ssq[3*NN+pn];
            float dp = (i == 0) ? 1.f : 1.f/(sqrtf(sqp) + 1e-8f);
            if (tt < pn) {
                const f16x8* Xr = (const f16x8*)(Xb + tt*SP);
                const f16x8* Xp = (const f16x8*)(Xb + pn*SP);
                float a0 = 0.f, a1 = 0.f, a2v = 0.f, a3 = 0.f;
                #pragma unroll
                for (int c = 0; c < 4; ++c) {
                    a0  = dot8(Xr[c*4 + 0], Xp[c*4 + 0], a0);
                    a1  = dot8(Xr[c*4 + 1], Xp[c*4 + 1], a1);
                    a2v = dot8(Xr[c*4 + 2], Xp[c*4 + 2], a2v);
                    a3  = dot8(Xr[c*4 + 3], Xp[c*4 + 3], a3);
                }
                float zd = (a0 + a1) + (a2v + a3);
                float sqj = ssq[tt] + ssq[NN+tt] + ssq[2*NN+tt] + ssq[3*NN+tt];
                float dj = (i == 0) ? 1.f : 1.f/(sqrtf(sqj) + 1e-8f);
                p_keep = 1.f/(1.f + expf(-0.5f*zd*dj*dp));
                f16 pf = (f16)p_keep;
                outbs[bb][pn*NN + tt] = p_keep;
                outbs[bb][tt*NN + pn] = p_keep;
                Gn[pn*GS + tt] = pf;
                Gn[tt*GS + pn] = pf;
            }
            sprob[bb][tt] = p_keep;
        }
    };

    auto P4c = [&](int bb, int i, int pn, float p_keep) {
        const int tloc = t - bb*512;
        if ((unsigned)tloc < NN) {
            const int tt = tloc;
            float pa = sprob[bb][lane];
            float pb = sprob[bb][lane + 64];
            float sp = ((lane < pn) ? pa : 0.f) + ((lane + 64 < pn) ? pb : 0.f);
            #pragma unroll
            for (int m2 = 1; m2 < 64; m2 <<= 1) sp += __shfl_xor(sp, m2);
            float dold = sd[bb][tt];
            float rsC = srows[bb][tt] + srows[bb][NN+tt]
                      + srows[bb][2*NN+tt] + srows[bb][3*NN+tt] + dold*dold;
            float dgC = sdiag[bb][tt];
            float rsM = (tt < pn) ? (rsC + p_keep)
                      : ((tt == pn) ? (sp + dgC) : rsC);
            float dnew = 1.f/sqrtf(rsM + 1.f + 1e-8f);
            sd[bb][tt] = dnew;
            dfs[bb][tt] = (f16)dnew;
            sdiag[bb][tt] = dnew*dnew*(dgC + 1.f);
            Gb[bb][(i & 1) ^ 1][tt*GS + tt] = (f16)dgC;
        }
    };

    run_mma(0, (f16)1.0f, (f16)1.0f);
    run_mma(1, (f16)1.0f, (f16)1.0f);
    __syncthreads();

    for (int i = 0; i < NN; ++i) {
        const int pn = i + 1;
        P2(0, i);
        P2(1, i);
        __syncthreads();
        float p_keep = 0.f;
        if (pn < NN) {
            P4(0, i, pn, p_keep);
            P4(1, i, pn, p_keep);
        }
        __syncthreads();
        if (pn < NN) {
            P4c(0, i, pn, p_keep);
            P4c(1, i, pn, p_keep);
        }
        __syncthreads();
    }
}

extern "C" void kernel_launch(void* const* d_in, const int* in_sizes, int n_in,
                              void* d_out, int out_size, void* d_ws, size_t ws_size,
                              hipStream_t stream) {
    const float* x  = (const float*)d_in[0];
    const float* W  = (const float*)d_in[1];
    const float* bb = (const float*)d_in[2];
    float* out = (float*)d_out;
    f16* gws = (f16*)d_ws;   // needs 8 * 2 * 128*128 * 2B = 512 KB

    const size_t shmem = (size_t)(4*NN*SP + 2*NN)*sizeof(f16)
                       + (size_t)(2*(NN + NN + NN + 4*NN + 4*NN))*sizeof(float);
    hipFuncSetAttribute((const void*)gcn_gen_kernel,
                        hipFuncAttributeMaxDynamicSharedMemorySize, (int)shmem);
    gcn_gen_kernel<<<4, 1024, shmem, stream>>>(x, W, bb, out, gws);
}

// Round 12
// 842.199 us; speedup vs baseline: 2.9733x; 2.9733x over previous
//
#include <hip/hip_runtime.h>
#include <math.h>

// GCN generator: B=8, N=F=128. One block/batch, 1024 threads (16 waves).
// Round 12: round 9 structure exactly (795us), ONE change: the per-step
// prob computation (dot(X[tt],X[pn]) rows) is distributed across ALL 1024
// threads (row=t>>3, 16-f16 segment per thread, 3-shfl reduce) instead of
// running as a long serial chain in 2 waves after mm_a. 3 barriers/step.
//   P2: z = dr*(M.(d*u)) + dr^2 u fused + relu + ssq + z->X (au in regs)
//   P4: distributed prob dots + sigmoid/out/patches || mm_a u=(dv.z).W -> U
//   P4c: sp butterfly, degrees, diag track, Gn diag fix (t<128).

#define NN 128
#define SP 136

typedef _Float16 f16;
typedef _Float16 f16x8 __attribute__((ext_vector_type(8)));
typedef _Float16 f16x4 __attribute__((ext_vector_type(4)));
typedef _Float16 f16x2 __attribute__((ext_vector_type(2)));
typedef float f32x4 __attribute__((ext_vector_type(4)));

__device__ __forceinline__ f32x4 mm(f16x8 a, f16x8 b, f32x4 c) {
    return __builtin_amdgcn_mfma_f32_16x16x32_f16(a, b, c, 0, 0, 0);
}

__device__ __forceinline__ float rowdot8(f16x8 g, float acc) {
#if __has_builtin(__builtin_amdgcn_fdot2)
    const f16x2 one2 = {(f16)1.0f, (f16)1.0f};
    #pragma unroll
    for (int p = 0; p < 4; ++p) {
        f16x2 pr = {g[2*p], g[2*p+1]};
        acc = __builtin_amdgcn_fdot2(pr, one2, acc, false);
    }
#else
    #pragma unroll
    for (int e = 0; e < 8; ++e) acc += (float)g[e];
#endif
    return acc;
}

__device__ __forceinline__ float dot8(f16x8 a, f16x8 b, float acc) {
#if __has_builtin(__builtin_amdgcn_fdot2)
    #pragma unroll
    for (int p = 0; p < 4; ++p) {
        f16x2 pa = {a[2*p], a[2*p+1]};
        f16x2 pb = {b[2*p], b[2*p+1]};
        acc = __builtin_amdgcn_fdot2(pa, pb, acc, false);
    }
#else
    #pragma unroll
    for (int e = 0; e < 8; ++e) acc += (float)a[e]*(float)b[e];
#endif
    return acc;
}

__global__ __launch_bounds__(1024)
void gcn_gen_kernel(const float* __restrict__ gx,
                    const float* __restrict__ gW,
                    const float* __restrict__ gb,
                    float* __restrict__ gout)
{
    extern __shared__ char lds_raw[];
    f16* X     = (f16*)lds_raw;              // [128][136] UNNORM z [n][f]
    f16* U     = X + NN*SP;                  // [128][136] u = x_hat.W, [fo][m]
    f16* Gb0   = U + NN*SP;                  // [128][136] M-hat ping
    f16* Gb1   = Gb0 + NN*SP;                // [128][136] M-hat pong
    f16* s_df16  = Gb1 + NN*SP;              // [128] d (f16)
    float* s_d    = (float*)(s_df16 + NN);   // [128] d (f32)
    float* s_diag = s_d + NN;                // [128] diag of carried C
    float* s_prob = s_diag + NN;             // [128] probs this step
    float* s_rows = s_prob + NN;             // [4][128] rowsum quarters
    float* s_ssq  = s_rows + 4*NN;           // [4][128] ssq partials by wc

    const int b = blockIdx.x;
    const int t = threadIdx.x;
    const int lane = t & 63;
    const int w = t >> 6;
    const int wr = w >> 2, wc = w & 3;       // wave grid 4x4 (32x32 tile)
    const int lrow = lane & 15;
    const int lgrp = lane >> 4;
    const int r0 = wr*32 + lrow;
    const int r1 = r0 + 16;
    const int j8 = t >> 3, s8 = t & 7;       // prob-dot row / segment

    const float* xb = gx + (size_t)b*NN*NN;
    float* outb = gout + (size_t)b*NN*NN;

    const float bias0 = gb[wc*32 + lrow];
    const float bias1 = gb[wc*32 + 16 + lrow];

    // ---- W -> registers as B-fragments for mm_a (k=fi, col=fo) ----
    f16x8 Wh[4][2];
    #pragma unroll
    for (int ks = 0; ks < 4; ++ks)
    #pragma unroll
    for (int ct = 0; ct < 2; ++ct) {
        const int col = wc*32 + ct*16 + lrow;
        #pragma unroll
        for (int r = 0; r < 8; ++r)
            Wh[ks][ct][r] = (f16)gW[(ks*32 + lgrp*8 + r)*NN + col];
    }

    // ---- init: X = f16(x), G0 = I(raw), out = eye, vectors ----
    #pragma unroll
    for (int q = 0; q < 16; ++q) {
        int idx = q*1024 + t;
        int r = idx >> 7, c = idx & 127;
        float e = (r == c) ? 1.f : 0.f;
        X[r*SP + c] = (f16)xb[idx];
        Gb0[r*SP + c] = (f16)e;
        outb[idx] = e;
    }
    if (t < NN) {
        s_d[t] = 0.70710678f;
        s_df16[t] = (f16)0.70710678f;
        s_diag[t] = 1.f;
    }
    __syncthreads();

    // mm_a: u = (sv . X) . W -> U[fo][m] (f16) AND au regs (f32, own tile)
    f32x4 au[2][2];
    auto run_mma = [&](f16 sv0, f16 sv1) {
        f32x4 a2[2][2];
        #pragma unroll
        for (int rt = 0; rt < 2; ++rt)
        #pragma unroll
        for (int ct = 0; ct < 2; ++ct)
            a2[rt][ct] = (f32x4){0.f,0.f,0.f,0.f};
        #pragma unroll
        for (int ks = 0; ks < 4; ++ks) {
            const int ko = ks*32 + lgrp*8;
            f16x8 A0 = *(const f16x8*)(X + r0*SP + ko) * sv0;
            f16x8 A1 = *(const f16x8*)(X + r1*SP + ko) * sv1;
            a2[0][0] = mm(A0, Wh[ks][0], a2[0][0]);
            a2[0][1] = mm(A0, Wh[ks][1], a2[0][1]);
            a2[1][0] = mm(A1, Wh[ks][0], a2[1][0]);
            a2[1][1] = mm(A1, Wh[ks][1], a2[1][1]);
        }
        #pragma unroll
        for (int rt = 0; rt < 2; ++rt)
        #pragma unroll
        for (int ct = 0; ct < 2; ++ct) {
            f16x4 uv;
            #pragma unroll
            for (int q = 0; q < 4; ++q) uv[q] = (f16)a2[rt][ct][q];
            *(f16x4*)(U + (wc*32 + ct*16 + lrow)*SP + wr*32 + rt*16 + lgrp*4) = uv;
            au[rt][ct] = a2[rt][ct];
        }
    };
    run_mma((f16)1.0f, (f16)1.0f);
    __syncthreads();

    for (int i = 0; i < NN; ++i) {
        const int pn = i + 1;
        f16* Gc = (i & 1) ? Gb1 : Gb0;       // M-hat (patched C_{i-1})
        f16* Gn = (i & 1) ? Gb0 : Gb1;       // receives scaled carry C_i

        // ========== P2: z = dr*(M.(d*u)) + dr^2 u, fused update ==========
        f16x8 dcv[4];
        #pragma unroll
        for (int ks = 0; ks < 4; ++ks)
            dcv[ks] = *(const f16x8*)(s_df16 + ks*32 + lgrp*8);
        const f16 drh0 = s_df16[r0];
        const f16 drh1 = s_df16[r1];

        f32x4 acc[2][2];
        #pragma unroll
        for (int rt = 0; rt < 2; ++rt)
        #pragma unroll
        for (int ct = 0; ct < 2; ++ct)
            acc[rt][ct] = (f32x4){0.f,0.f,0.f,0.f};
        float rs0 = 0.f, rs1 = 0.f;
        #pragma unroll
        for (int ks = 0; ks < 4; ++ks) {
            const int ko = ks*32 + lgrp*8;
            f16x8 B0 = *(const f16x8*)(U + (wc*32 + lrow)*SP + ko) * dcv[ks];
            f16x8 B1 = *(const f16x8*)(U + (wc*32 + 16 + lrow)*SP + ko) * dcv[ks];
            f16x8 A0 = *(const f16x8*)(Gc + r0*SP + ko);
            f16x8 A1 = *(const f16x8*)(Gc + r1*SP + ko);
            acc[0][0] = mm(A0, B0, acc[0][0]);
            acc[0][1] = mm(A0, B1, acc[0][1]);
            acc[1][0] = mm(A1, B0, acc[1][0]);
            acc[1][1] = mm(A1, B1, acc[1][1]);
            if (ks == wc) {                   // own quarter: carry + rowsum
                f16x8 G0s = A0 * dcv[ks] * drh0;
                f16x8 G1s = A1 * dcv[ks] * drh1;
                *(f16x8*)(Gn + r0*SP + ko) = G0s;
                *(f16x8*)(Gn + r1*SP + ko) = G1s;
                rs0 = rowdot8(G0s, rs0);
                rs1 = rowdot8(G1s, rs1);
            }
        }
        rs0 += __shfl_xor(rs0, 16); rs0 += __shfl_xor(rs0, 32);
        rs1 += __shfl_xor(rs1, 16); rs1 += __shfl_xor(rs1, 32);
        if (lgrp == 0) {
            s_rows[wc*NN + r0] = rs0;
            s_rows[wc*NN + r1] = rs1;
        }

        // z = dr*(acc + dr*u) + bias, relu; store UNNORM z -> X
        const float4 dr4a = *(const float4*)(s_d + wr*32 + lgrp*4);
        const float4 dr4b = *(const float4*)(s_d + wr*32 + 16 + lgrp*4);
        float z[2][2][4];
        #pragma unroll
        for (int rt = 0; rt < 2; ++rt)
        #pragma unroll
        for (int ct = 0; ct < 2; ++ct) {
            const int col = wc*32 + ct*16 + lrow;
            #pragma unroll
            for (int q = 0; q < 4; ++q) {
                float dq = rt ? ((const float*)&dr4b)[q] : ((const float*)&dr4a)[q];
                float inner = fmaf(dq, au[rt][ct][q], acc[rt][ct][q]);
                float zv = fmaxf(fmaf(dq, inner, (ct ? bias1 : bias0)), 0.f);
                z[rt][ct][q] = zv;
                X[(wr*32 + rt*16 + lgrp*4 + q)*SP + col] = (f16)zv;
            }
        }
        {
            float ss[8];
            #pragma unroll
            for (int k = 0; k < 8; ++k) {
                float a = z[k>>2][0][k&3], c2 = z[k>>2][1][k&3];
                ss[k] = a*a + c2*c2;
            }
            #pragma unroll
            for (int k = 0; k < 8; ++k) {
                ss[k] += __shfl_xor(ss[k], 1);
                ss[k] += __shfl_xor(ss[k], 2);
                ss[k] += __shfl_xor(ss[k], 4);
                ss[k] += __shfl_xor(ss[k], 8);
            }
            if (lrow == 0) {
                #pragma unroll
                for (int k = 0; k < 8; ++k) {
                    int row = wr*32 + (k>>2)*16 + lgrp*4 + (k&3);
                    s_ssq[wc*NN + row] = ss[k];
                }
            }
        }
        __syncthreads();

        // ========== P4: distributed probs + mm_a (dv-scaled) ==========
        if (pn < NN) {
            // prob dots: row j8 (= t>>3), 16-f16 segment s8 per thread
            if (j8 < pn) {
                const f16x8* Xr = (const f16x8*)(X + j8*SP + s8*16);
                const f16x8* Xp = (const f16x8*)(X + pn*SP + s8*16);
                float a0 = dot8(Xr[0], Xp[0], 0.f);
                a0 = dot8(Xr[1], Xp[1], a0);
                a0 += __shfl_xor(a0, 1);
                a0 += __shfl_xor(a0, 2);
                a0 += __shfl_xor(a0, 4);
                if (s8 == 0) {
                    float sqp = s_ssq[pn] + s_ssq[NN+pn] + s_ssq[2*NN+pn] + s_ssq[3*NN+pn];
                    float sqj = s_ssq[j8] + s_ssq[NN+j8] + s_ssq[2*NN+j8] + s_ssq[3*NN+j8];
                    float dp = (i == 0) ? 1.f : 1.f/(sqrtf(sqp) + 1e-8f);
                    float dj = (i == 0) ? 1.f : 1.f/(sqrtf(sqj) + 1e-8f);
                    float p = 1.f/(1.f + expf(-0.5f*a0*dj*dp));
                    s_prob[j8] = p;
                    outb[pn*NN + j8] = p;
                    outb[j8*NN + pn] = p;
                    f16 pf = (f16)p;
                    Gn[pn*SP + j8] = pf;      // patch row pn
                    Gn[j8*SP + pn] = pf;      // patch col pn
                }
            } else if (s8 == 0) {
                s_prob[j8] = 0.f;
            }

            f16 dvh[2];
            #pragma unroll
            for (int rt = 0; rt < 2; ++rt) {
                const int row = wr*32 + rt*16 + lrow;
                float sq = s_ssq[row] + s_ssq[NN+row] + s_ssq[2*NN+row] + s_ssq[3*NN+row];
                float dv = (i == 0) ? 1.f : 1.f/(sqrtf(sq) + 1e-8f);
                dvh[rt] = (f16)fminf(dv, 60000.f);
            }
            run_mma(dvh[0], dvh[1]);
        }
        __syncthreads();

        // ========== P4c: degrees/diag (t<128), tiny ==========
        if (pn < NN && t < NN) {
            const int tt = t;
            float pa = s_prob[lane];
            float pb = s_prob[lane + 64];
            float sp = ((lane < pn) ? pa : 0.f) + ((lane + 64 < pn) ? pb : 0.f);
            #pragma unroll
            for (int m2 = 1; m2 < 64; m2 <<= 1) sp += __shfl_xor(sp, m2);
            float p_keep = s_prob[tt];
            float dold = s_d[tt];
            float rsC = s_rows[tt] + s_rows[NN+tt] + s_rows[2*NN+tt] + s_rows[3*NN+tt]
                      + dold*dold;                    // rowsum(C_i)_t
            float dgC = s_diag[tt];                   // diag(C_i)_t
            float rsM = (tt < pn) ? (rsC + p_keep)
                      : ((tt == pn) ? (sp + dgC) : rsC);
            float dnew = 1.f/sqrtf(rsM + 1.f + 1e-8f);
            s_d[tt] = dnew;
            s_df16[tt] = (f16)dnew;
            s_diag[tt] = dnew*dnew*(dgC + 1.f);       // diag(C_{i+1})
            Gn[tt*SP + tt] = (f16)dgC;                // fix stored diag
        }
        __syncthreads();
    }
}

extern "C" void kernel_launch(void* const* d_in, const int* in_sizes, int n_in,
                              void* d_out, int out_size, void* d_ws, size_t ws_size,
                              hipStream_t stream) {
    const float* x  = (const float*)d_in[0];
    const float* W  = (const float*)d_in[1];
    const float* bb = (const float*)d_in[2];
    float* out = (float*)d_out;

    const size_t shmem = (size_t)(4*NN*SP + NN)*sizeof(f16)
                       + (size_t)(3*NN + 4*NN + 4*NN)*sizeof(float);
    hipFuncSetAttribute((const void*)gcn_gen_kernel,
                        hipFuncAttributeMaxDynamicSharedMemorySize, (int)shmem);
    gcn_gen_kernel<<<8, 1024, shmem, stream>>>(x, W, bb, out);
}

// Round 13
// 540.889 us; speedup vs baseline: 4.6296x; 1.5571x over previous
//
#include <hip/hip_runtime.h>
#include <math.h>

// GCN generator: B=8, N=F=128. One block/batch, 1024 threads (16 waves).
// Round 13: round 9 structure (3 barriers/step) with mm_b TRANSPOSED via
// C's symmetry (z^T = u^T.C): output fragments hold 4 consecutive fo ->
// f16x4 X writes (was 16 scalar f16, 4-way conflicts), ssq reduce 2x2 shfl
// (was 8x4). +I folded into stored diagonal (diag := dgC+1, init 2.0):
// kills the d^2*u epilogue term, the au register carry, and P4c's dold^2
// fixup; carry diag becomes automatically correct.
//   P2: patch-read Gc, A=U*dcv, B=Gc rows; acc=z^T; carry quarter ks==wr;
//       epilogue z=dn*acc+bias, relu, f16x4->X, ssq
//   P4: mm_a u=(dv.z).W -> U (16 waves) + t<128 tail: prob dots, sigmoid,
//       out writes, Gn row/col-pn patches
//   P4c: t<128: sp butterfly, degrees, diag:=dgC+1, s_diag update.

#define NN 128
#define SP 136

typedef _Float16 f16;
typedef _Float16 f16x8 __attribute__((ext_vector_type(8)));
typedef _Float16 f16x4 __attribute__((ext_vector_type(4)));
typedef _Float16 f16x2 __attribute__((ext_vector_type(2)));
typedef float f32x4 __attribute__((ext_vector_type(4)));

__device__ __forceinline__ f32x4 mm(f16x8 a, f16x8 b, f32x4 c) {
    return __builtin_amdgcn_mfma_f32_16x16x32_f16(a, b, c, 0, 0, 0);
}

__device__ __forceinline__ float rowdot8(f16x8 g, float acc) {
#if __has_builtin(__builtin_amdgcn_fdot2)
    const f16x2 one2 = {(f16)1.0f, (f16)1.0f};
    #pragma unroll
    for (int p = 0; p < 4; ++p) {
        f16x2 pr = {g[2*p], g[2*p+1]};
        acc = __builtin_amdgcn_fdot2(pr, one2, acc, false);
    }
#else
    #pragma unroll
    for (int e = 0; e < 8; ++e) acc += (float)g[e];
#endif
    return acc;
}

__device__ __forceinline__ float dot8(f16x8 a, f16x8 b, float acc) {
#if __has_builtin(__builtin_amdgcn_fdot2)
    #pragma unroll
    for (int p = 0; p < 4; ++p) {
        f16x2 pa = {a[2*p], a[2*p+1]};
        f16x2 pb = {b[2*p], b[2*p+1]};
        acc = __builtin_amdgcn_fdot2(pa, pb, acc, false);
    }
#else
    #pragma unroll
    for (int e = 0; e < 8; ++e) acc += (float)a[e]*(float)b[e];
#endif
    return acc;
}

__global__ __launch_bounds__(1024)
void gcn_gen_kernel(const float* __restrict__ gx,
                    const float* __restrict__ gW,
                    const float* __restrict__ gb,
                    float* __restrict__ gout)
{
    extern __shared__ char lds_raw[];
    f16* X     = (f16*)lds_raw;              // [128][136] UNNORM z [n][f]
    f16* U     = X + NN*SP;                  // [128][136] u = x_hat.W, [fo][m]
    f16* Gb0   = U + NN*SP;                  // [128][136] M-hat' ping (diag+1)
    f16* Gb1   = Gb0 + NN*SP;                // [128][136] M-hat' pong
    f16* s_df16  = Gb1 + NN*SP;              // [128] d (f16)
    float* s_d    = (float*)(s_df16 + NN);   // [128] d (f32)
    float* s_diag = s_d + NN;                // [128] diag of carried C
    float* s_prob = s_diag + NN;             // [128] probs this step
    float* s_rows = s_prob + NN;             // [4][128] rowsum quarters (by wr)
    float* s_ssq  = s_rows + 4*NN;           // [4][128] ssq partials (by wr)

    const int b = blockIdx.x;
    const int t = threadIdx.x;
    const int lane = t & 63;
    const int w = t >> 6;
    const int wr = w >> 2, wc = w & 3;       // wave grid: wr=fo-block, wc=n-block
    const int lrow = lane & 15;
    const int lgrp = lane >> 4;
    const int r0 = wr*32 + lrow;             // U/X row (fo or n for mm_a)
    const int r1 = r0 + 16;
    const int n0 = wc*32 + lrow;             // Gc/X n-row for mm_b B-side
    const int n1 = n0 + 16;

    const float* xb = gx + (size_t)b*NN*NN;
    float* outb = gout + (size_t)b*NN*NN;

    // bias indexed by fo = wr*32 + rt*16 + lgrp*4 + q
    const float4 bv0 = *(const float4*)(gb + wr*32 + lgrp*4);
    const float4 bv1 = *(const float4*)(gb + wr*32 + 16 + lgrp*4);

    // ---- W -> registers as B-fragments for mm_a (k=fi, col=fo) ----
    f16x8 Wh[4][2];
    #pragma unroll
    for (int ks = 0; ks < 4; ++ks)
    #pragma unroll
    for (int ct = 0; ct < 2; ++ct) {
        const int col = wc*32 + ct*16 + lrow;
        #pragma unroll
        for (int r = 0; r < 8; ++r)
            Wh[ks][ct][r] = (f16)gW[(ks*32 + lgrp*8 + r)*NN + col];
    }

    // ---- init: X = f16(x), G0 = I with diag 2.0 (+I fold), out = eye ----
    #pragma unroll
    for (int q = 0; q < 16; ++q) {
        int idx = q*1024 + t;
        int r = idx >> 7, c = idx & 127;
        float e = (r == c) ? 1.f : 0.f;
        X[r*SP + c] = (f16)xb[idx];
        Gb0[r*SP + c] = (f16)(e * 2.f);      // M' = I + I
        outb[idx] = e;
    }
    if (t < NN) {
        s_d[t] = 0.70710678f;
        s_df16[t] = (f16)0.70710678f;
        s_diag[t] = 1.f;                     // diag(C_0) = 1
    }
    __syncthreads();

    // mm_a: u = (sv . X) . W -> U[fo][m]
    auto run_mma = [&](f16 sv0, f16 sv1) {
        f32x4 a2[2][2];
        #pragma unroll
        for (int rt = 0; rt < 2; ++rt)
        #pragma unroll
        for (int ct = 0; ct < 2; ++ct)
            a2[rt][ct] = (f32x4){0.f,0.f,0.f,0.f};
        #pragma unroll
        for (int ks = 0; ks < 4; ++ks) {
            const int ko = ks*32 + lgrp*8;
            f16x8 A0 = *(const f16x8*)(X + r0*SP + ko) * sv0;
            f16x8 A1 = *(const f16x8*)(X + r1*SP + ko) * sv1;
            a2[0][0] = mm(A0, Wh[ks][0], a2[0][0]);
            a2[0][1] = mm(A0, Wh[ks][1], a2[0][1]);
            a2[1][0] = mm(A1, Wh[ks][0], a2[1][0]);
            a2[1][1] = mm(A1, Wh[ks][1], a2[1][1]);
        }
        #pragma unroll
        for (int rt = 0; rt < 2; ++rt)
        #pragma unroll
        for (int ct = 0; ct < 2; ++ct) {
            f16x4 uv;
            #pragma unroll
            for (int q = 0; q < 4; ++q) uv[q] = (f16)a2[rt][ct][q];
            *(f16x4*)(U + (wc*32 + ct*16 + lrow)*SP + wr*32 + rt*16 + lgrp*4) = uv;
        }
    };
    run_mma((f16)1.0f, (f16)1.0f);
    __syncthreads();

    for (int i = 0; i < NN; ++i) {
        const int pn = i + 1;
        f16* Gc = (i & 1) ? Gb1 : Gb0;       // M-hat' (patched, diag = dgC+1)
        f16* Gn = (i & 1) ? Gb0 : Gb1;       // receives scaled carry

        // ========== P2: z^T = (U*dcv) . Gc-rows; carry; epilogue ==========
        f16x8 dcv[4];
        #pragma unroll
        for (int ks = 0; ks < 4; ++ks)
            dcv[ks] = *(const f16x8*)(s_df16 + ks*32 + lgrp*8);
        const f16 dn0h = s_df16[n0];
        const f16 dn1h = s_df16[n1];

        f32x4 acc[2][2];                     // [rt=fo][ct=n]
        #pragma unroll
        for (int rt = 0; rt < 2; ++rt)
        #pragma unroll
        for (int ct = 0; ct < 2; ++ct)
            acc[rt][ct] = (f32x4){0.f,0.f,0.f,0.f};
        float rs0 = 0.f, rs1 = 0.f;
        #pragma unroll
        for (int ks = 0; ks < 4; ++ks) {
            const int ko = ks*32 + lgrp*8;
            f16x8 A0 = *(const f16x8*)(U + r0*SP + ko) * dcv[ks];
            f16x8 A1 = *(const f16x8*)(U + r1*SP + ko) * dcv[ks];
            f16x8 B0 = *(const f16x8*)(Gc + n0*SP + ko);
            f16x8 B1 = *(const f16x8*)(Gc + n1*SP + ko);
            acc[0][0] = mm(A0, B0, acc[0][0]);
            acc[0][1] = mm(A0, B1, acc[0][1]);
            acc[1][0] = mm(A1, B0, acc[1][0]);
            acc[1][1] = mm(A1, B1, acc[1][1]);
            if (ks == wr) {                  // own (n in wc, m in wr) quarter
                f16x8 G0s = B0 * dcv[ks] * dn0h;
                f16x8 G1s = B1 * dcv[ks] * dn1h;
                *(f16x8*)(Gn + n0*SP + ko) = G0s;
                *(f16x8*)(Gn + n1*SP + ko) = G1s;
                rs0 = rowdot8(G0s, rs0);
                rs1 = rowdot8(G1s, rs1);
            }
        }
        rs0 += __shfl_xor(rs0, 16); rs0 += __shfl_xor(rs0, 32);
        rs1 += __shfl_xor(rs1, 16); rs1 += __shfl_xor(rs1, 32);
        if (lgrp == 0) {
            s_rows[wr*NN + n0] = rs0;
            s_rows[wr*NN + n1] = rs1;
        }

        // epilogue: z = dn * acc + bias(fo), relu; f16x4 -> X; ssq
        const float dn[2] = { s_d[n0], s_d[n1] };
        float z[2][2][4];
        float ssc[2] = {0.f, 0.f};
        #pragma unroll
        for (int rt = 0; rt < 2; ++rt)
        #pragma unroll
        for (int ct = 0; ct < 2; ++ct) {
            f16x4 xv;
            #pragma unroll
            for (int q = 0; q < 4; ++q) {
                float bq = rt ? ((const float*)&bv1)[q] : ((const float*)&bv0)[q];
                float zv = fmaxf(fmaf(dn[ct], acc[rt][ct][q], bq), 0.f);
                z[rt][ct][q] = zv;
                ssc[ct] = fmaf(zv, zv, ssc[ct]);
                xv[q] = (f16)zv;
            }
            *(f16x4*)(X + (wc*32 + ct*16 + lrow)*SP + wr*32 + rt*16 + lgrp*4) = xv;
        }
        ssc[0] += __shfl_xor(ssc[0], 16); ssc[0] += __shfl_xor(ssc[0], 32);
        ssc[1] += __shfl_xor(ssc[1], 16); ssc[1] += __shfl_xor(ssc[1], 32);
        if (lgrp == 0) {
            s_ssq[wr*NN + n0] = ssc[0];
            s_ssq[wr*NN + n1] = ssc[1];
        }
        __syncthreads();

        // ========== P4: mm_a (dv-scaled) + t<128 tail ==========
        float p_keep = 0.f;
        if (pn < NN) {
            f16 dvh[2];
            #pragma unroll
            for (int rt = 0; rt < 2; ++rt) {
                const int row = wr*32 + rt*16 + lrow;
                float sq = s_ssq[row] + s_ssq[NN+row] + s_ssq[2*NN+row] + s_ssq[3*NN+row];
                float dv = (i == 0) ? 1.f : 1.f/(sqrtf(sq) + 1e-8f);
                dvh[rt] = (f16)fminf(dv, 60000.f);
            }
            run_mma(dvh[0], dvh[1]);

            if (t < NN) {
                const int tt = t;
                f16* GnP = Gn;
                float sqp = s_ssq[pn] + s_ssq[NN+pn] + s_ssq[2*NN+pn] + s_ssq[3*NN+pn];
                float dp = (i == 0) ? 1.f : 1.f/(sqrtf(sqp) + 1e-8f);
                if (tt < pn) {
                    const f16x8* Xr = (const f16x8*)(X + tt*SP);
                    const f16x8* Xp = (const f16x8*)(X + pn*SP);
                    float a0 = 0.f, a1 = 0.f, a2v = 0.f, a3 = 0.f;
                    #pragma unroll
                    for (int c = 0; c < 4; ++c) {
                        a0  = dot8(Xr[c*4 + 0], Xp[c*4 + 0], a0);
                        a1  = dot8(Xr[c*4 + 1], Xp[c*4 + 1], a1);
                        a2v = dot8(Xr[c*4 + 2], Xp[c*4 + 2], a2v);
                        a3  = dot8(Xr[c*4 + 3], Xp[c*4 + 3], a3);
                    }
                    float zd = (a0 + a1) + (a2v + a3);
                    float sqj = s_ssq[tt] + s_ssq[NN+tt] + s_ssq[2*NN+tt] + s_ssq[3*NN+tt];
                    float dj = (i == 0) ? 1.f : 1.f/(sqrtf(sqj) + 1e-8f);
                    p_keep = 1.f/(1.f + expf(-0.5f*zd*dj*dp));
                    f16 pf = (f16)p_keep;
                    outb[pn*NN + tt] = p_keep;
                    outb[tt*NN + pn] = p_keep;
                    GnP[pn*SP + tt] = pf;     // patch row pn
                    GnP[tt*SP + pn] = pf;     // patch col pn
                }
                s_prob[tt] = p_keep;
            }
        }
        __syncthreads();

        // ========== P4c: degrees/diag (t<128) ==========
        if (pn < NN && t < NN) {
            const int tt = t;
            float pa = s_prob[lane];
            float pb = s_prob[lane + 64];
            float sp = ((lane < pn) ? pa : 0.f) + ((lane + 64 < pn) ? pb : 0.f);
            #pragma unroll
            for (int m2 = 1; m2 < 64; m2 <<= 1) sp += __shfl_xor(sp, m2);
            // rowsum(C_i) = local (carry diag auto-correct with +I fold)
            float rsC = s_rows[tt] + s_rows[NN+tt] + s_rows[2*NN+tt] + s_rows[3*NN+tt];
            float dgC = s_diag[tt];                   // diag(C_i)_t
            float rsM = (tt < pn) ? (rsC + p_keep)
                      : ((tt == pn) ? (sp + dgC) : rsC);
            float dnew = 1.f/sqrtf(rsM + 1.f + 1e-8f);
            s_d[tt] = dnew;
            s_df16[tt] = (f16)dnew;
            s_diag[tt] = dnew*dnew*(dgC + 1.f);       // diag(C_{i+1})
            Gn[tt*SP + tt] = (f16)(dgC + 1.f);        // stored diag = dgC+1
        }
        __syncthreads();
    }
}

extern "C" void kernel_launch(void* const* d_in, const int* in_sizes, int n_in,
                              void* d_out, int out_size, void* d_ws, size_t ws_size,
                              hipStream_t stream) {
    const float* x  = (const float*)d_in[0];
    const float* W  = (const float*)d_in[1];
    const float* bb = (const float*)d_in[2];
    float* out = (float*)d_out;

    const size_t shmem = (size_t)(4*NN*SP + NN)*sizeof(f16)
                       + (size_t)(3*NN + 4*NN + 4*NN)*sizeof(float);
    hipFuncSetAttribute((const void*)gcn_gen_kernel,
                        hipFuncAttributeMaxDynamicSharedMemorySize, (int)shmem);
    gcn_gen_kernel<<<8, 1024, shmem, stream>>>(x, W, bb, out);
}